// Round 13
// baseline (411.123 us; speedup 1.0000x reference)
//
#include <hip/hip_runtime.h>
#include <math.h>

// GPT-2 attention block, bf16-MFMA pipeline. B=2, T=2048, C=1024, H=16, D=64.
// R12: attn widened to 32 q-rows/wave (two 16-row subtiles) — doubles MFMA
// work per serial chain traversal (R5 vs R11 proved TLP doesn't hide the
// chain; amortization is the lever). Grid 2048 blocks; K loaded in halves to
// keep peak live regs ~112 < 128 cap. Numerics per q-row identical to R11.

#define TSEQ 2048
#define NHD  16
#define DH   64
#define CDIM 1024

typedef __attribute__((ext_vector_type(8))) short bf16x8;
typedef __attribute__((ext_vector_type(4))) float f32x4;

#define MFMA(a, b, c) __builtin_amdgcn_mfma_f32_16x16x32_bf16((a), (b), (c), 0, 0, 0)

__device__ __forceinline__ ushort f2bf(float f) {
    unsigned u = __builtin_bit_cast(unsigned, f);
    u += 0x7FFFu + ((u >> 16) & 1u);          // RNE
    return (ushort)(u >> 16);
}
__device__ __forceinline__ float bf2f(ushort h) {
    unsigned u = ((unsigned)h) << 16;
    return __builtin_bit_cast(float, u);
}

// ---------------------------------------------------------------- prepass ---
__global__ __launch_bounds__(256) void cast_k(const float* __restrict__ in,
                                              ushort* __restrict__ out, int n4) {
    int i = blockIdx.x * 256 + threadIdx.x;
    const int stride = gridDim.x * 256;
    for (; i < n4; i += stride) {
        float4 f = ((const float4*)in)[i];
        ushort4 o;
        o.x = f2bf(f.x); o.y = f2bf(f.y); o.z = f2bf(f.z); o.w = f2bf(f.w);
        ((ushort4*)out)[i] = o;
    }
}

// in fp32 [R][C] -> out bf16 [C][R]
__global__ __launch_bounds__(256) void transpose_k(const float* __restrict__ in,
                                                   ushort* __restrict__ out,
                                                   int R, int C) {
    __shared__ float t[32][33];
    const int tx = threadIdx.x, ty = threadIdx.y;     // 32 x 8
    const int c0 = blockIdx.x * 32, r0 = blockIdx.y * 32;
#pragma unroll
    for (int i = 0; i < 4; ++i)
        t[ty + i * 8][tx] = in[(size_t)(r0 + ty + i * 8) * C + c0 + tx];
    __syncthreads();
#pragma unroll
    for (int i = 0; i < 4; ++i)
        out[(size_t)(c0 + ty + i * 8) * R + r0 + tx] = f2bf(t[tx][ty + i * 8]);
}

// ------------------------------------------------------------------- qkv ----
// X[4096][1024] bf16, Wt[3072][1024] bf16 (n-major). 128x128 tile, 4 waves 2x2.
__global__ __launch_bounds__(256) void qkv_k(const ushort* __restrict__ X,
                                             const ushort* __restrict__ Wt,
                                             const float* __restrict__ bias,
                                             ushort* __restrict__ qb,
                                             ushort* __restrict__ kb,
                                             ushort* __restrict__ vtb) {
    const int fid = blockIdx.x;                 // 768 = 8 * 96 (bijective swizzle)
    const int nf = (fid & 7) * 96 + (fid >> 3);
    const int mt = nf / 24, nt = nf % 24;
    const int m0 = mt * 128, n0 = nt * 128;
    const int tid = threadIdx.x, lane = tid & 63, w = tid >> 6;
    const int l15 = lane & 15, g = lane >> 4;
    const int wm = w >> 1, wn = w & 1;

    const ushort* Ar[4]; const ushort* Br[4];
#pragma unroll
    for (int s = 0; s < 4; ++s) {
        Ar[s] = X  + (size_t)(m0 + wm * 64 + s * 16 + l15) * 1024 + g * 8;
        Br[s] = Wt + (size_t)(n0 + wn * 64 + s * 16 + l15) * 1024 + g * 8;
    }
    f32x4 acc[4][4] = {};
    bf16x8 a[4], b[4], a2[4], b2[4];
#pragma unroll
    for (int s = 0; s < 4; ++s) { a[s] = *(const bf16x8*)(Ar[s]); b[s] = *(const bf16x8*)(Br[s]); }

    for (int kk = 0; kk < 1024; kk += 32) {
        if (kk + 32 < 1024) {
#pragma unroll
            for (int s = 0; s < 4; ++s) {
                a2[s] = *(const bf16x8*)(Ar[s] + kk + 32);
                b2[s] = *(const bf16x8*)(Br[s] + kk + 32);
            }
        }
#pragma unroll
        for (int i = 0; i < 4; ++i)
#pragma unroll
            for (int j = 0; j < 4; ++j)
                acc[i][j] = MFMA(a[i], b[j], acc[i][j]);
#pragma unroll
        for (int s = 0; s < 4; ++s) { a[s] = a2[s]; b[s] = b2[s]; }
    }
    // epilogue: D col = lane&15 (n), row = g*4+reg (m within 16-subtile)
#pragma unroll
    for (int j = 0; j < 4; ++j) {
        const int n = n0 + wn * 64 + j * 16 + l15;
        const float bv = bias[n];
        const int which = n >> 10;
        const int c = n & 1023, h = c >> 6, d = c & 63;
#pragma unroll
        for (int i = 0; i < 4; ++i)
#pragma unroll
            for (int r = 0; r < 4; ++r) {
                const int m = m0 + wm * 64 + i * 16 + g * 4 + r;
                const int bb = m >> 11, t = m & 2047;
                const float val = acc[i][j][r] + bv;
                const int bh = bb * NHD + h;
                if (which == 0)
                    qb[((size_t)bh * TSEQ + t) * 64 + d] = f2bf(val * 0.125f);
                else if (which == 1)
                    kb[((size_t)bh * TSEQ + t) * 64 + d] = f2bf(val);
                else
                    vtb[((size_t)bh * 64 + d) * TSEQ + t] = f2bf(val);
            }
    }
}

// ------------------------------------------------------------- attention ----
// Split-K flash attention, 32 q-rows per wave (2 subtiles). Block = 4 waves on
// one (bh, 32-q-row group); wave w takes K-tiles t = w, w+4, ... Swapped QK^T
// (S^T = K*Q^T), per-wave online softmax, PV via O^T = V^T*P^T; LDS merge.
__global__ __launch_bounds__(256, 4) void attn_k(const ushort* __restrict__ Q,
                                                 const ushort* __restrict__ K,
                                                 const ushort* __restrict__ VT,
                                                 ushort* __restrict__ Yh,
                                                 ushort* __restrict__ Yl) {
    __shared__ ushort P[4][2][16][72];  // per-wave, per-subtile P bounce
    __shared__ float Om[4][16][66];     // partial O^T merge (reused per subtile)
    __shared__ float Mw[4][2][16];
    __shared__ float Lw[4][2][16];

    const int fid = blockIdx.x;         // 2048 = 8 XCD * 256
    const int nf = (fid & 7) * 256 + (fid >> 3);
    const int bh = nf >> 6, q32 = nf & 63;
    const int tid = threadIdx.x, w = tid >> 6, lane = tid & 63;
    const int l15 = lane & 15, g = lane >> 4;
    const int q0 = q32 * 32;

    const ushort* Qb = Q  + (size_t)bh * TSEQ * 64;
    const ushort* Kb = K  + (size_t)bh * TSEQ * 64;
    const ushort* Vb = VT + (size_t)bh * 64 * TSEQ;

    bf16x8 qf[2][2];
#pragma unroll
    for (int u = 0; u < 2; ++u) {
        const ushort* qr = Qb + (size_t)(q0 + u * 16 + l15) * 64 + g * 8;
        qf[u][0] = *(const bf16x8*)(qr);
        qf[u][1] = *(const bf16x8*)(qr + 32);
    }

    f32x4 o[2][4] = {};
    float m_run[2] = {-INFINITY, -INFINITY};
    float l_run[2] = {0.f, 0.f};
    const int nT = q0 / 64 + 1;         // covers row q0+31 for q0%64 in {0,32}

    for (int t = w; t < nT; t += 4) {
        const int kv0 = t * 64;
        f32x4 s4[2][4] = {};
        // QK^T in two K-halves (caps live registers)
#pragma unroll
        for (int h = 0; h < 2; ++h) {
            bf16x8 ak[2][2];
#pragma unroll
            for (int ss = 0; ss < 2; ++ss) {
                const int s = h * 2 + ss;
                const ushort* kr = Kb + (size_t)(kv0 + s * 16 + l15) * 64 + g * 8;
                ak[ss][0] = *(const bf16x8*)(kr);
                ak[ss][1] = *(const bf16x8*)(kr + 32);
            }
#pragma unroll
            for (int u = 0; u < 2; ++u)
#pragma unroll
                for (int ss = 0; ss < 2; ++ss) {
                    const int s = h * 2 + ss;
                    s4[u][s] = MFMA(ak[ss][0], qf[u][0], s4[u][s]);
                    s4[u][s] = MFMA(ak[ss][1], qf[u][1], s4[u][s]);
                }
        }
        // V loads issued here — latency hides under the softmax VALU/DS chain
        bf16x8 av[4][2];
#pragma unroll
        for (int s = 0; s < 4; ++s) {
            const ushort* vr = Vb + (size_t)(s * 16 + l15) * TSEQ + kv0 + g * 8;
            av[s][0] = *(const bf16x8*)(vr);
            av[s][1] = *(const bf16x8*)(vr + 32);
        }
        if (kv0 + 63 > q0) {            // diagonal-overlapping tile only
#pragma unroll
            for (int u = 0; u < 2; ++u)
#pragma unroll
                for (int s = 0; s < 4; ++s)
#pragma unroll
                    for (int r = 0; r < 4; ++r) {
                        const int kg = kv0 + s * 16 + g * 4 + r;
                        if (kg > q0 + u * 16 + l15) s4[u][s][r] = -INFINITY;
                    }
        }
        // online softmax, both subtiles (independent chains interleave)
        float mx[2];
#pragma unroll
        for (int u = 0; u < 2; ++u) {
            mx[u] = -INFINITY;
#pragma unroll
            for (int s = 0; s < 4; ++s)
#pragma unroll
                for (int r = 0; r < 4; ++r) mx[u] = fmaxf(mx[u], s4[u][s][r]);
        }
        mx[0] = fmaxf(mx[0], __shfl_xor(mx[0], 16));
        mx[1] = fmaxf(mx[1], __shfl_xor(mx[1], 16));
        mx[0] = fmaxf(mx[0], __shfl_xor(mx[0], 32));
        mx[1] = fmaxf(mx[1], __shfl_xor(mx[1], 32));
        float lsum[2], alpha[2];
#pragma unroll
        for (int u = 0; u < 2; ++u) {
            const float mnew = fmaxf(m_run[u], mx[u]);
            alpha[u] = __expf(m_run[u] - mnew);
            lsum[u] = 0.f;
#pragma unroll
            for (int s = 0; s < 4; ++s) {
                float p0 = __expf(s4[u][s][0] - mnew);
                float p1 = __expf(s4[u][s][1] - mnew);
                float p2 = __expf(s4[u][s][2] - mnew);
                float p3 = __expf(s4[u][s][3] - mnew);
                lsum[u] += (p0 + p1) + (p2 + p3);
                ushort4 pw;
                pw.x = f2bf(p0); pw.y = f2bf(p1); pw.z = f2bf(p2); pw.w = f2bf(p3);
                *(ushort4*)&P[w][u][l15][s * 16 + g * 4] = pw;
            }
            m_run[u] = mnew;
        }
        lsum[0] += __shfl_xor(lsum[0], 16);
        lsum[1] += __shfl_xor(lsum[1], 16);
        lsum[0] += __shfl_xor(lsum[0], 32);
        lsum[1] += __shfl_xor(lsum[1], 32);
#pragma unroll
        for (int u = 0; u < 2; ++u) {
            l_run[u] = l_run[u] * alpha[u] + lsum[u];
#pragma unroll
            for (int s = 0; s < 4; ++s)
#pragma unroll
                for (int r = 0; r < 4; ++r) o[u][s][r] *= alpha[u];
        }
        // same-wave LDS write->read (DS in-order per wave, no barrier)
        bf16x8 pb[2][2];
#pragma unroll
        for (int u = 0; u < 2; ++u) {
            pb[u][0] = *(const bf16x8*)&P[w][u][l15][g * 8];
            pb[u][1] = *(const bf16x8*)&P[w][u][l15][32 + g * 8];
        }
#pragma unroll
        for (int u = 0; u < 2; ++u)
#pragma unroll
            for (int s = 0; s < 4; ++s) {
                o[u][s] = MFMA(av[s][0], pb[u][0], o[u][s]);
                o[u][s] = MFMA(av[s][1], pb[u][1], o[u][s]);
            }
    }

    // ---- publish per-wave state, merge across 4 waves (one pass/subtile) ----
    if (g == 0) {
        Mw[w][0][l15] = m_run[0]; Mw[w][1][l15] = m_run[1];
        Lw[w][0][l15] = l_run[0]; Lw[w][1][l15] = l_run[1];
    }
#pragma unroll
    for (int u = 0; u < 2; ++u) {
        if (u) __syncthreads();         // WAR: pass-0 reads done before rewrite
#pragma unroll
        for (int s = 0; s < 4; ++s) {
            *(float2*)&Om[w][l15][s * 16 + g * 4]     = make_float2(o[u][s][0], o[u][s][1]);
            *(float2*)&Om[w][l15][s * 16 + g * 4 + 2] = make_float2(o[u][s][2], o[u][s][3]);
        }
        __syncthreads();
        const float m_tot = fmaxf(fmaxf(Mw[0][u][l15], Mw[1][u][l15]),
                                  fmaxf(Mw[2][u][l15], Mw[3][u][l15]));
        float l_tot = 0.f;
        f32x4 od = {};
#pragma unroll
        for (int j = 0; j < 4; ++j) {
            const float sc = __expf(Mw[j][u][l15] - m_tot);  // idle wave -> 0
            l_tot += Lw[j][u][l15] * sc;
            const float2 p0 = *(const float2*)&Om[j][l15][w * 16 + g * 4];
            const float2 p1 = *(const float2*)&Om[j][l15][w * 16 + g * 4 + 2];
            od[0] += p0.x * sc; od[1] += p0.y * sc;
            od[2] += p1.x * sc; od[3] += p1.y * sc;
        }
        const float inv = 1.f / l_tot;
        const int trow = q0 + u * 16 + l15;
        const size_t base = ((size_t)(bh >> 4) * TSEQ + trow) * CDIM
                            + (bh & 15) * 64 + w * 16 + g * 4;
        ushort4 hv, lv;
        float v;
        v = od[0] * inv; hv.x = f2bf(v); lv.x = f2bf(v - bf2f(hv.x));
        v = od[1] * inv; hv.y = f2bf(v); lv.y = f2bf(v - bf2f(hv.y));
        v = od[2] * inv; hv.z = f2bf(v); lv.z = f2bf(v - bf2f(hv.z));
        v = od[3] * inv; hv.w = f2bf(v); lv.w = f2bf(v - bf2f(hv.w));
        *(ushort4*)&Yh[base] = hv;
        *(ushort4*)&Yl[base] = lv;
    }
}

// ------------------------------------------------------------------ proj ----
// out = (Yh + Yl) @ W_proj + b, split-precision A. 64x64 tile, 4-wave split-K
// (256 K each), LDS f32 merge. Wt n-major [1024][1024].
__global__ __launch_bounds__(256, 3) void proj_k(const ushort* __restrict__ Yh,
                                                 const ushort* __restrict__ Yl,
                                                 const ushort* __restrict__ Wt,
                                                 const float* __restrict__ bias,
                                                 float* __restrict__ out) {
    __shared__ float S[64][68];                 // [n][m] (pad 68: float4-aligned)
    const int fid = blockIdx.x;                 // 1024 = 8 * 128
    const int nf = (fid & 7) * 128 + (fid >> 3);
    const int mt = nf >> 4, nt = nf & 15;       // 64 x 16 tiles
    const int m0 = mt * 64, n0 = nt * 64;
    const int tid = threadIdx.x, w = tid >> 6, lane = tid & 63;
    const int l15 = lane & 15, g = lane >> 4;
    const int k0 = w * 256;                     // this wave's K slice

    const ushort* Ah[4]; const ushort* Al[4]; const ushort* Br[4];
#pragma unroll
    for (int s = 0; s < 4; ++s) {
        const size_t arow = (size_t)(m0 + s * 16 + l15) * 1024 + k0 + g * 8;
        Ah[s] = Yh + arow;
        Al[s] = Yl + arow;
        Br[s] = Wt + (size_t)(n0 + s * 16 + l15) * 1024 + k0 + g * 8;
    }
    f32x4 acc[4][4] = {};
#pragma unroll 2
    for (int kk = 0; kk < 256; kk += 32) {
        bf16x8 ah[4], al[4], b[4];
#pragma unroll
        for (int s = 0; s < 4; ++s) {
            ah[s] = *(const bf16x8*)(Ah[s] + kk);
            al[s] = *(const bf16x8*)(Al[s] + kk);
            b[s]  = *(const bf16x8*)(Br[s] + kk);
        }
#pragma unroll
        for (int i = 0; i < 4; ++i)
#pragma unroll
            for (int j = 0; j < 4; ++j) {
                acc[i][j] = MFMA(ah[i], b[j], acc[i][j]);
                acc[i][j] = MFMA(al[i], b[j], acc[i][j]);
            }
    }
    // sequential wave merge: S[n][m] (+= per wave), 4 barriers
    for (int ww = 0; ww < 4; ++ww) {
        if (ww == w) {
#pragma unroll
            for (int i = 0; i < 4; ++i)
#pragma unroll
                for (int j = 0; j < 4; ++j) {
                    f32x4* dst = (f32x4*)&S[j * 16 + l15][i * 16 + g * 4];
                    if (ww == 0) *dst = acc[i][j];
                    else         *dst = *dst + acc[i][j];
                }
        }
        __syncthreads();
    }
    // cooperative epilogue: thread -> row m = tid>>2, n-range (tid&3)*16..+15
    const int m = tid >> 2;
    const int nq = (tid & 3) * 16;
    float* orow = out + (size_t)(m0 + m) * 1024 + n0 + nq;
#pragma unroll
    for (int u = 0; u < 16; u += 4) {
        const float4 bv = *(const float4*)&bias[n0 + nq + u];
        float4 vo;
        vo.x = S[nq + u + 0][m] + bv.x;
        vo.y = S[nq + u + 1][m] + bv.y;
        vo.z = S[nq + u + 2][m] + bv.z;
        vo.w = S[nq + u + 3][m] + bv.w;
        *(float4*)&orow[u] = vo;
    }
}

// ---------------------------------------------------------------------------
extern "C" void kernel_launch(void* const* d_in, const int* in_sizes, int n_in,
                              void* d_out, int out_size, void* d_ws, size_t ws_size,
                              hipStream_t stream) {
    (void)in_sizes; (void)n_in; (void)out_size; (void)ws_size;
    const float* x      = (const float*)d_in[0];
    // d_in[1] = attn_mask (causal triu -> structural)
    const float* W_attn = (const float*)d_in[2];
    const float* b_attn = (const float*)d_in[3];
    const float* W_proj = (const float*)d_in[4];
    const float* b_proj = (const float*)d_in[5];
    float* out = (float*)d_out;

    ushort* xb  = (ushort*)d_ws;          // 4096*1024
    ushort* wta = xb  + 4194304;          // 3072*1024
    ushort* wtp = wta + 3145728;          // 1024*1024
    ushort* qb  = wtp + 1048576;          // [32][2048][64]
    ushort* kb  = qb  + 4194304;
    ushort* vtb = kb  + 4194304;          // [32][64][2048]
    ushort* yh  = vtb + 4194304;          // [4096][1024]
    ushort* yl  = yh  + 4194304;

    cast_k<<<1024, 256, 0, stream>>>(x, xb, 4194304 / 4);
    transpose_k<<<dim3(96, 32), dim3(32, 8), 0, stream>>>(W_attn, wta, 1024, 3072);
    transpose_k<<<dim3(32, 32), dim3(32, 8), 0, stream>>>(W_proj, wtp, 1024, 1024);
    qkv_k<<<768, 256, 0, stream>>>(xb, wta, b_attn, qb, kb, vtb);
    attn_k<<<2048, 256, 0, stream>>>(qb, kb, vtb, yh, yl);
    proj_k<<<1024, 256, 0, stream>>>(yh, yl, wtp, b_proj, out);
}

// Round 14
// 329.138 us; speedup vs baseline: 1.2491x; 1.2491x over previous
//
#include <hip/hip_runtime.h>
#include <math.h>

// GPT-2 attention block, bf16-MFMA pipeline. B=2, T=2048, C=1024, H=16, D=64.
// R14: attn reverted to R11 (R12/13's 32-row widening spilled: WRITE 278 MB).
// qkv rebuilt as LDS-staged 128x128xBK64 GEMM (reg-staged, XOR-swizzled LDS,
// 2-barrier loop) — qkv was ~160 us latency-bound direct-from-global.

#define TSEQ 2048
#define NHD  16
#define DH   64
#define CDIM 1024

typedef __attribute__((ext_vector_type(8))) short bf16x8;
typedef __attribute__((ext_vector_type(4))) float f32x4;

#define MFMA(a, b, c) __builtin_amdgcn_mfma_f32_16x16x32_bf16((a), (b), (c), 0, 0, 0)

__device__ __forceinline__ ushort f2bf(float f) {
    unsigned u = __builtin_bit_cast(unsigned, f);
    u += 0x7FFFu + ((u >> 16) & 1u);          // RNE
    return (ushort)(u >> 16);
}
__device__ __forceinline__ float bf2f(ushort h) {
    unsigned u = ((unsigned)h) << 16;
    return __builtin_bit_cast(float, u);
}

// ---------------------------------------------------------------- prepass ---
__global__ __launch_bounds__(256) void cast_k(const float* __restrict__ in,
                                              ushort* __restrict__ out, int n4) {
    int i = blockIdx.x * 256 + threadIdx.x;
    const int stride = gridDim.x * 256;
    for (; i < n4; i += stride) {
        float4 f = ((const float4*)in)[i];
        ushort4 o;
        o.x = f2bf(f.x); o.y = f2bf(f.y); o.z = f2bf(f.z); o.w = f2bf(f.w);
        ((ushort4*)out)[i] = o;
    }
}

// in fp32 [R][C] -> out bf16 [C][R]
__global__ __launch_bounds__(256) void transpose_k(const float* __restrict__ in,
                                                   ushort* __restrict__ out,
                                                   int R, int C) {
    __shared__ float t[32][33];
    const int tx = threadIdx.x, ty = threadIdx.y;     // 32 x 8
    const int c0 = blockIdx.x * 32, r0 = blockIdx.y * 32;
#pragma unroll
    for (int i = 0; i < 4; ++i)
        t[ty + i * 8][tx] = in[(size_t)(r0 + ty + i * 8) * C + c0 + tx];
    __syncthreads();
#pragma unroll
    for (int i = 0; i < 4; ++i)
        out[(size_t)(c0 + ty + i * 8) * R + r0 + tx] = f2bf(t[tx][ty + i * 8]);
}

// ------------------------------------------------------------------- qkv ----
// X[4096][1024] bf16, Wt[3072][1024] bf16 (n-major). LDS-staged 128x128 tile,
// BK=64, 4 waves 2x2 (64x64/wave). XOR-swizzle on 16B chunk index: LDS rows
// are 128 B (stride = 32 banks), so linear layout would put all 16 lanes of a
// fragment read on one bank span (16-way). chunk ^= (row&7) -> <=2-way (free).
// Per-wave MFMA order/operands bit-identical to the direct-global version.
__global__ __launch_bounds__(256, 3) void qkv_k(const ushort* __restrict__ X,
                                                const ushort* __restrict__ Wt,
                                                const float* __restrict__ bias,
                                                ushort* __restrict__ qb,
                                                ushort* __restrict__ kb,
                                                ushort* __restrict__ vtb) {
    __shared__ ushort Al[128][64];   // 16 KB
    __shared__ ushort Bl[128][64];   // 16 KB  (Bl[n][k])

    const int fid = blockIdx.x;                 // 768 = 8 * 96 (bijective swizzle)
    const int nf = (fid & 7) * 96 + (fid >> 3);
    const int mt = nf / 24, nt = nf % 24;
    const int m0 = mt * 128, n0 = nt * 128;
    const int tid = threadIdx.x, lane = tid & 63, w = tid >> 6;
    const int l15 = lane & 15, g = lane >> 4;
    const int wm = w >> 1, wn = w & 1;

    // staging map: chunk c = tid + 256*i -> row = c>>3, ch = c&7 (16B chunks)
    int srow[4], sch[4];
#pragma unroll
    for (int i = 0; i < 4; ++i) {
        const int c = tid + 256 * i;
        srow[i] = c >> 3;
        sch[i] = c & 7;
    }

    bf16x8 ra[4], rb[4];
#pragma unroll
    for (int i = 0; i < 4; ++i) {   // tile 0 global->reg
        ra[i] = *(const bf16x8*)&X [(size_t)(m0 + srow[i]) * 1024 + sch[i] * 8];
        rb[i] = *(const bf16x8*)&Wt[(size_t)(n0 + srow[i]) * 1024 + sch[i] * 8];
    }

    f32x4 acc[4][4] = {};

    for (int k0 = 0; k0 < 1024; k0 += 64) {
        __syncthreads();             // previous compute done; LDS reusable
#pragma unroll
        for (int i = 0; i < 4; ++i) {
            const int sc = (sch[i] ^ (srow[i] & 7)) * 8;
            *(bf16x8*)&Al[srow[i]][sc] = ra[i];
            *(bf16x8*)&Bl[srow[i]][sc] = rb[i];
        }
        __syncthreads();             // tiles visible
        if (k0 + 64 < 1024) {        // next tile global->reg; hides under compute
#pragma unroll
            for (int i = 0; i < 4; ++i) {
                ra[i] = *(const bf16x8*)&X [(size_t)(m0 + srow[i]) * 1024 + k0 + 64 + sch[i] * 8];
                rb[i] = *(const bf16x8*)&Wt[(size_t)(n0 + srow[i]) * 1024 + k0 + 64 + sch[i] * 8];
            }
        }
#pragma unroll
        for (int kk = 0; kk < 2; ++kk) {   // k-slices 0, 32
            bf16x8 af[4], bf[4];
#pragma unroll
            for (int s = 0; s < 4; ++s) {
                const int arow = wm * 64 + s * 16 + l15;
                af[s] = *(const bf16x8*)&Al[arow][((kk * 4 + g) ^ (arow & 7)) * 8];
                const int brow = wn * 64 + s * 16 + l15;
                bf[s] = *(const bf16x8*)&Bl[brow][((kk * 4 + g) ^ (brow & 7)) * 8];
            }
#pragma unroll
            for (int i = 0; i < 4; ++i)
#pragma unroll
                for (int j = 0; j < 4; ++j)
                    acc[i][j] = MFMA(af[i], bf[j], acc[i][j]);
        }
    }
    // epilogue: D col = lane&15 (n), row = g*4+reg (m within 16-subtile)
#pragma unroll
    for (int j = 0; j < 4; ++j) {
        const int n = n0 + wn * 64 + j * 16 + l15;
        const float bv = bias[n];
        const int which = n >> 10;
        const int c = n & 1023, h = c >> 6, d = c & 63;
#pragma unroll
        for (int i = 0; i < 4; ++i)
#pragma unroll
            for (int r = 0; r < 4; ++r) {
                const int m = m0 + wm * 64 + i * 16 + g * 4 + r;
                const int bb = m >> 11, t = m & 2047;
                const float val = acc[i][j][r] + bv;
                const int bh = bb * NHD + h;
                if (which == 0)
                    qb[((size_t)bh * TSEQ + t) * 64 + d] = f2bf(val * 0.125f);
                else if (which == 1)
                    kb[((size_t)bh * TSEQ + t) * 64 + d] = f2bf(val);
                else
                    vtb[((size_t)bh * 64 + d) * TSEQ + t] = f2bf(val);
            }
    }
}

// ------------------------------------------------------------- attention ----
// R11 version (measured 151 us, no spill). Split-K flash attention: block =
// 4 waves on one (bh, 16-q-row group); wave w takes K-tiles t = w, w+4, ...
// Swapped QK^T (S^T = K*Q^T), per-wave online softmax, PV via O^T = V^T*P^T;
// LDS merge. No K double-buffer; V loaded after QK^T (K/V never co-resident).
__global__ __launch_bounds__(256, 4) void attn_k(const ushort* __restrict__ Q,
                                                 const ushort* __restrict__ K,
                                                 const ushort* __restrict__ VT,
                                                 ushort* __restrict__ Yh,
                                                 ushort* __restrict__ Yl) {
    __shared__ ushort P[4][16][72];    // per-wave P bounce [w][q][k]
    __shared__ float Om[4][16][66];    // partial O^T: [w][q][d]
    __shared__ float Mw[4][16];
    __shared__ float Lw[4][16];

    const int fid = blockIdx.x;        // 4096 = 8 XCD * 512 (4 heads/XCD in L2)
    const int nf = (fid & 7) * 512 + (fid >> 3);
    const int bh = nf >> 7, q16 = nf & 127;
    const int tid = threadIdx.x, w = tid >> 6, lane = tid & 63;
    const int l15 = lane & 15, g = lane >> 4;
    const int q0 = q16 * 16;

    const ushort* Qb = Q  + (size_t)bh * TSEQ * 64;
    const ushort* Kb = K  + (size_t)bh * TSEQ * 64;
    const ushort* Vb = VT + (size_t)bh * 64 * TSEQ;

    bf16x8 qf0 = *(const bf16x8*)(Qb + (size_t)(q0 + l15) * 64 + g * 8);
    bf16x8 qf1 = *(const bf16x8*)(Qb + (size_t)(q0 + l15) * 64 + 32 + g * 8);

    f32x4 o[4] = {};
    float m_run = -INFINITY, l_run = 0.f;
    const int nT = q0 / 64 + 1;        // q0 % 64 <= 48, so this is exact

    for (int t = w; t < nT; t += 4) {
        const int kv0 = t * 64;
        bf16x8 ak[4][2];
#pragma unroll
        for (int s = 0; s < 4; ++s) {
            const ushort* kr = Kb + (size_t)(kv0 + s * 16 + l15) * 64 + g * 8;
            ak[s][0] = *(const bf16x8*)(kr);
            ak[s][1] = *(const bf16x8*)(kr + 32);
        }
        f32x4 s4[4] = {};
#pragma unroll
        for (int s = 0; s < 4; ++s) {
            s4[s] = MFMA(ak[s][0], qf0, s4[s]);
            s4[s] = MFMA(ak[s][1], qf1, s4[s]);
        }
        // V loads issued here (no dependency on s4) — latency hides under the
        // softmax VALU chain below; ak registers are dead, allocator reuses.
        bf16x8 av[4][2];
#pragma unroll
        for (int s = 0; s < 4; ++s) {
            const ushort* vr = Vb + (size_t)(s * 16 + l15) * TSEQ + kv0 + g * 8;
            av[s][0] = *(const bf16x8*)(vr);
            av[s][1] = *(const bf16x8*)(vr + 32);
        }
        if (kv0 + 63 > q0) {           // diagonal tile only
#pragma unroll
            for (int s = 0; s < 4; ++s)
#pragma unroll
                for (int r = 0; r < 4; ++r) {
                    const int kg = kv0 + s * 16 + g * 4 + r;
                    if (kg > q0 + l15) s4[s][r] = -INFINITY;
                }
        }
        float mx = -INFINITY;
#pragma unroll
        for (int s = 0; s < 4; ++s)
#pragma unroll
            for (int r = 0; r < 4; ++r) mx = fmaxf(mx, s4[s][r]);
        mx = fmaxf(mx, __shfl_xor(mx, 16));
        mx = fmaxf(mx, __shfl_xor(mx, 32));
        const float mnew = fmaxf(m_run, mx);
        const float alpha = __expf(m_run - mnew);
        float lsum = 0.f;
#pragma unroll
        for (int s = 0; s < 4; ++s) {
            float p0 = __expf(s4[s][0] - mnew);
            float p1 = __expf(s4[s][1] - mnew);
            float p2 = __expf(s4[s][2] - mnew);
            float p3 = __expf(s4[s][3] - mnew);
            lsum += (p0 + p1) + (p2 + p3);
            ushort4 pw;
            pw.x = f2bf(p0); pw.y = f2bf(p1); pw.z = f2bf(p2); pw.w = f2bf(p3);
            *(ushort4*)&P[w][l15][s * 16 + g * 4] = pw;
        }
        lsum += __shfl_xor(lsum, 16);
        lsum += __shfl_xor(lsum, 32);
        l_run = l_run * alpha + lsum;
        m_run = mnew;
#pragma unroll
        for (int s = 0; s < 4; ++s)
#pragma unroll
            for (int r = 0; r < 4; ++r) o[s][r] *= alpha;
        // same-wave LDS write->read: DS pipe in-order per wave, no barrier
        bf16x8 pb0 = *(const bf16x8*)&P[w][l15][g * 8];
        bf16x8 pb1 = *(const bf16x8*)&P[w][l15][32 + g * 8];
#pragma unroll
        for (int s = 0; s < 4; ++s) {
            o[s] = MFMA(av[s][0], pb0, o[s]);
            o[s] = MFMA(av[s][1], pb1, o[s]);
        }
    }

    // ---- publish partial state, merge across the 4 waves ----
    if (g == 0) { Mw[w][l15] = m_run; Lw[w][l15] = l_run; }
#pragma unroll
    for (int s = 0; s < 4; ++s) {
        *(float2*)&Om[w][l15][s * 16 + g * 4]     = make_float2(o[s][0], o[s][1]);
        *(float2*)&Om[w][l15][s * 16 + g * 4 + 2] = make_float2(o[s][2], o[s][3]);
    }
    __syncthreads();

    const float m0v = Mw[0][l15], m1v = Mw[1][l15], m2v = Mw[2][l15], m3v = Mw[3][l15];
    const float m_tot = fmaxf(fmaxf(m0v, m1v), fmaxf(m2v, m3v));
    float l_tot = 0.f;
    f32x4 od = {};
#pragma unroll
    for (int j = 0; j < 4; ++j) {
        const float sc = __expf(Mw[j][l15] - m_tot);   // exp(-inf - m) = 0 for idle waves
        l_tot += Lw[j][l15] * sc;
        const float2 p0 = *(const float2*)&Om[j][l15][w * 16 + g * 4];
        const float2 p1 = *(const float2*)&Om[j][l15][w * 16 + g * 4 + 2];
        od[0] += p0.x * sc; od[1] += p0.y * sc;
        od[2] += p1.x * sc; od[3] += p1.y * sc;
    }
    const float inv = 1.f / l_tot;
    const int trow = q0 + l15;
    const size_t base = ((size_t)(bh >> 4) * TSEQ + trow) * CDIM + (bh & 15) * 64
                        + w * 16 + g * 4;               // wave w owns d-block w
    ushort4 hv, lv;
    float v;
    v = od[0] * inv; hv.x = f2bf(v); lv.x = f2bf(v - bf2f(hv.x));
    v = od[1] * inv; hv.y = f2bf(v); lv.y = f2bf(v - bf2f(hv.y));
    v = od[2] * inv; hv.z = f2bf(v); lv.z = f2bf(v - bf2f(hv.z));
    v = od[3] * inv; hv.w = f2bf(v); lv.w = f2bf(v - bf2f(hv.w));
    *(ushort4*)&Yh[base] = hv;
    *(ushort4*)&Yl[base] = lv;
}

// ------------------------------------------------------------------ proj ----
// out = (Yh + Yl) @ W_proj + b, split-precision A. 64x64 tile, 4-wave split-K
// (256 K each), LDS f32 merge. Wt n-major [1024][1024].
__global__ __launch_bounds__(256, 3) void proj_k(const ushort* __restrict__ Yh,
                                                 const ushort* __restrict__ Yl,
                                                 const ushort* __restrict__ Wt,
                                                 const float* __restrict__ bias,
                                                 float* __restrict__ out) {
    __shared__ float S[64][68];                 // [n][m] (pad 68: float4-aligned)
    const int fid = blockIdx.x;                 // 1024 = 8 * 128
    const int nf = (fid & 7) * 128 + (fid >> 3);
    const int mt = nf >> 4, nt = nf & 15;       // 64 x 16 tiles
    const int m0 = mt * 64, n0 = nt * 64;
    const int tid = threadIdx.x, w = tid >> 6, lane = tid & 63;
    const int l15 = lane & 15, g = lane >> 4;
    const int k0 = w * 256;                     // this wave's K slice

    const ushort* Ah[4]; const ushort* Al[4]; const ushort* Br[4];
#pragma unroll
    for (int s = 0; s < 4; ++s) {
        const size_t arow = (size_t)(m0 + s * 16 + l15) * 1024 + k0 + g * 8;
        Ah[s] = Yh + arow;
        Al[s] = Yl + arow;
        Br[s] = Wt + (size_t)(n0 + s * 16 + l15) * 1024 + k0 + g * 8;
    }
    f32x4 acc[4][4] = {};
#pragma unroll 2
    for (int kk = 0; kk < 256; kk += 32) {
        bf16x8 ah[4], al[4], b[4];
#pragma unroll
        for (int s = 0; s < 4; ++s) {
            ah[s] = *(const bf16x8*)(Ah[s] + kk);
            al[s] = *(const bf16x8*)(Al[s] + kk);
            b[s]  = *(const bf16x8*)(Br[s] + kk);
        }
#pragma unroll
        for (int i = 0; i < 4; ++i)
#pragma unroll
            for (int j = 0; j < 4; ++j) {
                acc[i][j] = MFMA(ah[i], b[j], acc[i][j]);
                acc[i][j] = MFMA(al[i], b[j], acc[i][j]);
            }
    }
    // sequential wave merge: S[n][m] (+= per wave), 4 barriers
    for (int ww = 0; ww < 4; ++ww) {
        if (ww == w) {
#pragma unroll
            for (int i = 0; i < 4; ++i)
#pragma unroll
                for (int j = 0; j < 4; ++j) {
                    f32x4* dst = (f32x4*)&S[j * 16 + l15][i * 16 + g * 4];
                    if (ww == 0) *dst = acc[i][j];
                    else         *dst = *dst + acc[i][j];
                }
        }
        __syncthreads();
    }
    // cooperative epilogue: thread -> row m = tid>>2, n-range (tid&3)*16..+15
    const int m = tid >> 2;
    const int nq = (tid & 3) * 16;
    float* orow = out + (size_t)(m0 + m) * 1024 + n0 + nq;
#pragma unroll
    for (int u = 0; u < 16; u += 4) {
        const float4 bv = *(const float4*)&bias[n0 + nq + u];
        float4 vo;
        vo.x = S[nq + u + 0][m] + bv.x;
        vo.y = S[nq + u + 1][m] + bv.y;
        vo.z = S[nq + u + 2][m] + bv.z;
        vo.w = S[nq + u + 3][m] + bv.w;
        *(float4*)&orow[u] = vo;
    }
}

// ---------------------------------------------------------------------------
extern "C" void kernel_launch(void* const* d_in, const int* in_sizes, int n_in,
                              void* d_out, int out_size, void* d_ws, size_t ws_size,
                              hipStream_t stream) {
    (void)in_sizes; (void)n_in; (void)out_size; (void)ws_size;
    const float* x      = (const float*)d_in[0];
    // d_in[1] = attn_mask (causal triu -> structural)
    const float* W_attn = (const float*)d_in[2];
    const float* b_attn = (const float*)d_in[3];
    const float* W_proj = (const float*)d_in[4];
    const float* b_proj = (const float*)d_in[5];
    float* out = (float*)d_out;

    ushort* xb  = (ushort*)d_ws;          // 4096*1024
    ushort* wta = xb  + 4194304;          // 3072*1024
    ushort* wtp = wta + 3145728;          // 1024*1024
    ushort* qb  = wtp + 1048576;          // [32][2048][64]
    ushort* kb  = qb  + 4194304;
    ushort* vtb = kb  + 4194304;          // [32][64][2048]
    ushort* yh  = vtb + 4194304;          // [4096][1024]
    ushort* yl  = yh  + 4194304;

    cast_k<<<1024, 256, 0, stream>>>(x, xb, 4194304 / 4);
    transpose_k<<<dim3(96, 32), dim3(32, 8), 0, stream>>>(W_attn, wta, 1024, 3072);
    transpose_k<<<dim3(32, 32), dim3(32, 8), 0, stream>>>(W_proj, wtp, 1024, 1024);
    qkv_k<<<768, 256, 0, stream>>>(xb, wta, b_attn, qb, kb, vtb);
    attn_k<<<4096, 256, 0, stream>>>(qb, kb, vtb, yh, yl);
    proj_k<<<1024, 256, 0, stream>>>(yh, yl, wtp, b_proj, out);
}